// Round 1
// 118.765 us; speedup vs baseline: 1.0879x; 1.0879x over previous
//
#include <hip/hip_runtime.h>
#include <hip/hip_bf16.h>

// M=3 models, B=16 images, N=512 boxes, K=M*N=1536/image, 12 classes, IoU 0.5.
// Output (B,K,5) f32 = score-sorted (x1,y1,x2,y2,score) * keep.
#define MM 3
#define BB 16
#define NN 512
#define KK 1536          // 24*64
#define NW 24            // 64-bit mask words per row

// ---------------- Kernel A: barrier-free rank sort + scatter ----------------
// key = (~bits(score*w) << 16) | origIdx : ascending u64 == descending score,
// ties by ascending original index (matches stable argsort(-s)). Scores >= 0
// so the bit pattern is order-preserving; score recovered bit-exactly.
// 128 threads/block (2 waves), ONE element/thread: per-thread rank loop is
// 768 ulonglong2 broadcast reads x 2 u64 compares (~9.2k issue cycles), half
// of the old 2-elem/thread version; the 2 waves hide the LDS broadcast reads
// under VALU issue. grid (12,16) = 192 blocks, <=1 block/CU.
__global__ __launch_bounds__(128) void rank_kernel(
    const float* __restrict__ boxes, const float* __restrict__ scores,
    const int* __restrict__ labels, const float* __restrict__ weights,
    float* __restrict__ sboxes, float* __restrict__ sscores,
    int* __restrict__ slabels, float* __restrict__ sarea,
    unsigned long long* __restrict__ flagw) {
  int b = blockIdx.y, tid = threadIdx.x;
  __shared__ unsigned long long kl[KK];
  float w0 = weights[0], w1 = weights[1], w2 = weights[2];
  for (int t = tid; t < KK; t += 128) {
    int m = t >> 9, n = t & 511;
    float wm = (m == 0) ? w0 : ((m == 1) ? w1 : w2);
    float s = scores[(m * BB + b) * NN + n] * wm;
    kl[t] = ((unsigned long long)(~__float_as_uint(s)) << 16) | (unsigned)t;
  }
  if (blockIdx.x == 0 && tid < NW) flagw[b * NW + tid] = 0ULL;  // zero poison
  __syncthreads();
  int i0 = blockIdx.x * 128 + tid;
  unsigned long long k0 = kl[i0];
  int r0 = 0;
  const ulonglong2* k2 = (const ulonglong2*)kl;  // broadcast LDS reads
#pragma unroll 8
  for (int j = 0; j < KK / 2; ++j) {
    ulonglong2 kk = k2[j];
    r0 += (int)(kk.x < k0) + (int)(kk.y < k0);
  }
  int o = (int)(k0 & 0xFFFFu);
  int m = o >> 9, n = o & 511;
  float4 box = ((const float4*)boxes)[(m * BB + b) * NN + n];
  ((float4*)sboxes)[b * KK + r0] = box;
  sscores[b * KK + r0] = __uint_as_float(~(unsigned)(k0 >> 16));
  slabels[b * KK + r0] = labels[(m * BB + b) * NN + n];
  sarea[b * KK + r0] = (box.z - box.x) * (box.w - box.y);
}

// ---------------- Kernel B: 64x64 lower-triangular IoU tiles ----------------
// grid (300, 16): blockIdx.x enumerates tile pairs (rt,ct), ct<=rt. Wave w
// handles rows w*16..w*16+15; the 64 lanes are the 64 cols -> __ballot builds
// each mask word directly. Divide-free exact compare:
//   fl(inter/uni) > 0.5  <=>  inter > uni*(0.5+2^-25)   (exact in f64;
//   identical to 2*inter > uni*(1+2^-24), one f64 mul saved)
__global__ __launch_bounds__(256) void tile_kernel(
    const float* __restrict__ sboxes, const int* __restrict__ slabels,
    const float* __restrict__ sarea, unsigned long long* __restrict__ mat,
    unsigned long long* __restrict__ flagw) {
#pragma clang fp contract(off)
  int b = blockIdx.y, tid = threadIdx.x;
  int t = blockIdx.x;
  int rt = (int)((sqrtf(8.0f * (float)t + 1.0f) - 1.0f) * 0.5f);
  while ((rt + 1) * (rt + 2) / 2 <= t) ++rt;
  while (rt * (rt + 1) / 2 > t) --rt;
  int ct = t - rt * (rt + 1) / 2;   // 0 <= ct <= rt <= 23
  int rowbase = rt * 64, colbase = ct * 64;

  __shared__ float4 rb[64]; __shared__ float ra[64]; __shared__ int rl[64];
  __shared__ float4 cb[64]; __shared__ float ca[64]; __shared__ int cl[64];
  const float4* sb4 = (const float4*)sboxes;
  if (tid < 64) {
    rb[tid] = sb4[b * KK + rowbase + tid];
    ra[tid] = sarea[b * KK + rowbase + tid];
    rl[tid] = slabels[b * KK + rowbase + tid];
  } else if (tid < 128) {
    int u = tid - 64;
    cb[u] = sb4[b * KK + colbase + u];
    ca[u] = sarea[b * KK + colbase + u];
    cl[u] = slabels[b * KK + colbase + u];
  }
  __syncthreads();

  int lane = tid & 63, wave = tid >> 6;
  float4 bj = cb[lane]; float aj = ca[lane]; int lj = cl[lane];
  unsigned long long wflag = 0;
#pragma unroll 4
  for (int s = 0; s < 16; ++s) {
    int r = wave * 16 + s;
    float4 bi = rb[r];          // broadcast
    float ai = ra[r]; int li = rl[r];
    float iw = fminf(bi.z, bj.z) - fmaxf(bi.x, bj.x); iw = fmaxf(iw, 0.0f);
    float ih = fminf(bi.w, bj.w) - fmaxf(bi.y, bj.y); ih = fmaxf(ih, 0.0f);
    float inter = iw * ih;
    float uni = (ai + aj) - inter;                 // matches ref order, no fma
    bool sup = ((double)inter > (double)uni * (0.5 + 0x1p-25)) && (lj == li);
    unsigned long long bits = __ballot(sup);
    if (rt == ct) bits &= (1ULL << r) - 1ULL;      // keep only j < i
    if (lane == 0) mat[(size_t)(b * KK + rowbase + r) * NW + ct] = bits;
    if (bits) wflag |= 1ULL << r;
  }
  if (lane == 0 && wflag) atomicOr(&flagw[b * NW + rt], wflag);
}

// ---------------- Kernel C: chunked-LDS sequential scan + output ----------
// Wave 0 builds the flagged-row list; unflagged rows kept immediately. Then,
// per 256-row chunk, ALL 256 threads cooperatively stage the chunk's mask
// rows into LDS (parallel L2/L3 loads), and wave 0 scans from LDS — the
// per-iteration LDS read is independent of the keep chain, so it pipelines.
// NOTE: every __shfl here runs with ALL 64 lanes of wave 0 active — on CDNA,
// ds_bpermute returns 0 when the source lane is inactive (the R3 bug).
__global__ __launch_bounds__(256) void scan_kernel(
    const float* __restrict__ sboxes, const float* __restrict__ sscores,
    const unsigned long long* __restrict__ mat,
    const unsigned long long* __restrict__ flagw, float* __restrict__ out) {
  int b = blockIdx.x, tid = threadIdx.x;
  int lane = tid & 63, wave = tid >> 6;
  __shared__ unsigned long long mbuf[256 * NW];   // 48 KB chunk buffer
  __shared__ int list[KK];
  __shared__ unsigned long long keepLDS[NW];
  __shared__ unsigned long long flagLDS[NW];
  __shared__ int F_s;

  if (wave == 0) {
    unsigned long long fwl = (lane < NW) ? flagw[b * NW + lane] : 0ULL;
    if (lane < NW) flagLDS[lane] = fwl;
    int cnt = __popcll(fwl);
    int off = cnt;                       // inclusive prefix over 64 lanes
    for (int d = 1; d < 64; d <<= 1) {
      int o = __shfl_up(off, d);
      if (lane >= d) off += o;
    }
    int excl = off - cnt;
    unsigned long long w = fwl; int k = 0;
    while (w) {
      int r = __ffsll(w) - 1; w &= w - 1;
      list[excl + k] = lane * 64 + r; ++k;
    }
    int F = __shfl(off, 63);             // ALL lanes active for the shuffle
    if (lane == 0) F_s = F;
  }
  __syncthreads();
  int F = F_s;
  unsigned long long kw =
      (wave == 0 && lane < NW) ? ~flagLDS[lane] : 0ULL;  // unflagged -> kept

  for (int c0 = 0; c0 < F; c0 += 256) {
    int cn = min(256, F - c0);
    for (int x = tid; x < cn * NW; x += 256) {
      int q = x / NW, wd = x - q * NW;
      int i = list[c0 + q];
      mbuf[x] = (wd <= (i >> 6)) ? mat[(size_t)(b * KK + i) * NW + wd] : 0ULL;
    }
    __syncthreads();
    if (wave == 0) {
      for (int q = 0; q < cn; ++q) {
        int i = list[c0 + q];
        unsigned long long rw = (lane < NW) ? mbuf[q * NW + lane] : 0ULL;
        unsigned long long conf = __ballot((rw & kw) != 0ULL);
        if (conf == 0ULL && lane == (i >> 6)) kw |= 1ULL << (i & 63);
      }
    }
    __syncthreads();
  }
  if (wave == 0 && lane < NW) keepLDS[lane] = kw;
  __syncthreads();

  for (int e = tid; e < KK * 5; e += 256) {
    int row = e / 5, c = e - row * 5;
    bool k = (keepLDS[row >> 6] >> (row & 63)) & 1ULL;
    float v = 0.0f;
    if (k) v = (c < 4) ? sboxes[(size_t)(b * KK + row) * 4 + c]
                       : sscores[b * KK + row];
    out[(size_t)b * (KK * 5) + e] = v;
  }
}

extern "C" void kernel_launch(void* const* d_in, const int* in_sizes, int n_in,
                              void* d_out, int out_size, void* d_ws, size_t ws_size,
                              hipStream_t stream) {
  (void)in_sizes; (void)n_in; (void)out_size; (void)ws_size;
  const float* boxes   = (const float*)d_in[0];  // (M,B,N,4)
  const float* scores  = (const float*)d_in[1];  // (M,B,N)
  const int*   labels  = (const int*)d_in[2];    // (M,B,N)
  const float* weights = (const float*)d_in[3];  // (M,)
  float* out = (float*)d_out;                    // (B,K,5)

  // ws layout (bytes), total ~5.16 MB
  char* base = (char*)d_ws;
  float* sboxes  = (float*)(base + 0);                   // B*K*4 f32
  float* sscores = (float*)(base + 393216);              // B*K f32
  int*   slabels = (int*)  (base + 491520);              // B*K i32
  float* sarea   = (float*)(base + 589824);              // B*K f32
  unsigned long long* flagw = (unsigned long long*)(base + 688128); // B*NW u64
  unsigned long long* mat   = (unsigned long long*)(base + 691200); // B*K*NW u64

  rank_kernel<<<dim3(KK / 128, BB), 128, 0, stream>>>(
      boxes, scores, labels, weights, sboxes, sscores, slabels, sarea, flagw);
  tile_kernel<<<dim3(NW * (NW + 1) / 2, BB), 256, 0, stream>>>(
      sboxes, slabels, sarea, mat, flagw);
  scan_kernel<<<BB, 256, 0, stream>>>(sboxes, sscores, mat, flagw, out);
}